// Round 6
// baseline (75.660 us; speedup 1.0000x reference)
//
#include <hip/hip_runtime.h>

// DensityLoss: B=8, N=4096, radius=0.1, NSAMPLE=9, TOPK=5, H=0.12, EPS=1e-12
// Output: scalar mean over [B,N,TOPK-1] of (RADIUS - sqrt(ds)*exp(-ds/H^2))
//
// R6: grid-binned ball query. Per block: bin batch's 4096 points into a
// 10x10x10 cell grid in LDS (cell edge 0.1 = radius), then each query scans
// only its 27 neighbor cells (~110 candidates vs 4096). Qualifier set is
// identical to the R5 full scan (same fmaf diff-form predicate; a point
// outside the 27-cell neighborhood has dx>=0.1f on some axis -> ds > RAD2).
// First-9-by-original-index semantics preserved by collecting (idx, ds) of
// ALL qualifiers and ranking by index: slot = rank (<9), fill = rank-0 ds —
// exactly the reference's index-sorted ball-query slots.

#define NB 8
#define NPTS 4096
#define NS 9
#define NCELL 1000
#define RAD2 0.01f
#define H2 0.0144f
#define EPSV 1e-12f
#define SCALE (1.0f / 131072.0f)   // 1/(B*N*(TOPK-1)) = 1/(8*4096*4)
#define QCAP 64                    // qualifier list cap (E[count]≈17, P(>64)~0)

__global__ __launch_bounds__(1024) void density_loss_kernel(
    const float* __restrict__ pred, float* __restrict__ out) {
    __shared__ __align__(16) float spx[NPTS], spy[NPTS], spz[NPTS]; // binned SoA
    __shared__ unsigned short sidx[NPTS];     // original index per binned slot
    __shared__ int cellCnt[NCELL];
    __shared__ int cellStart[1008];           // exclusive prefix; [1000..] = 4096
    __shared__ float qds[16][QCAP];           // per-wave qualifier ds
    __shared__ int   qid[16][QCAP];           // per-wave qualifier original idx
    __shared__ float buf[64][NS];             // per-point slots (index-rank order)
    __shared__ int   cnts[64];
    __shared__ int   wtot[16], wtote[16];

    const int tid  = threadIdx.x;
    const int lane = tid & 63;
    const int wid  = tid >> 6;
    const int b    = blockIdx.x >> 6;                        // 64 blocks/batch
    const int nbase = ((blockIdx.x & 63) << 6) + (wid << 2); // 4 queries/wave
    const float* src = pred + (size_t)b * (NPTS * 3);

    if (tid < NCELL) cellCnt[tid] = 0;
    __syncthreads();

    // ---- Load 4 points/thread (coalesced float4), cell-id, count.
    float px[4], py[4], pz[4];
    int cid[4], off[4];
    {
        const float4* s4 = (const float4*)src;
        float4 A = s4[3 * tid], Bq = s4[3 * tid + 1], Cq = s4[3 * tid + 2];
        px[0] = A.x;  py[0] = A.y;  pz[0] = A.z;
        px[1] = A.w;  py[1] = Bq.x; pz[1] = Bq.y;
        px[2] = Bq.z; py[2] = Bq.w; pz[2] = Cq.x;
        px[3] = Cq.y; py[3] = Cq.z; pz[3] = Cq.w;
        #pragma unroll
        for (int k = 0; k < 4; ++k) {
            int cx = min((int)(px[k] * 10.0f), 9);
            int cy = min((int)(py[k] * 10.0f), 9);
            int cz = min((int)(pz[k] * 10.0f), 9);
            cid[k] = (cx * 10 + cy) * 10 + cz;
            off[k] = atomicAdd(&cellCnt[cid[k]], 1);
        }
    }
    __syncthreads();

    // ---- Exclusive scan cellCnt -> cellStart (wave shfl scan + wave totals).
    {
        int val = (tid < NCELL) ? cellCnt[tid] : 0;
        int incl = val;
        #pragma unroll
        for (int o = 1; o < 64; o <<= 1) {
            int t = __shfl_up(incl, o, 64);
            if (lane >= o) incl += t;
        }
        if (lane == 63) wtot[wid] = incl;
        __syncthreads();
        if (wid == 0) {
            int wv = (lane < 16) ? wtot[lane] : 0;
            int wi = wv;
            #pragma unroll
            for (int o = 1; o < 16; o <<= 1) {
                int t = __shfl_up(wi, o, 64);
                if (lane >= o) wi += t;
            }
            if (lane < 16) wtote[lane] = wi - wv;
        }
        __syncthreads();
        if (tid < 1008) cellStart[tid] = wtote[wid] + incl - val;
    }
    __syncthreads();

    // ---- Scatter into binned SoA, carrying original indices.
    #pragma unroll
    for (int k = 0; k < 4; ++k) {
        int pos = cellStart[cid[k]] + off[k];
        spx[pos] = px[k]; spy[pos] = py[k]; spz[pos] = pz[k];
        sidx[pos] = (unsigned short)((tid << 2) + k);
    }
    __syncthreads();

    // ---- Query phase: 4 queries per wave, 27-cell candidate gather.
    int qn = 0;  // wave-uniform qualifier count
    for (int q = 0; q < 4; ++q) {
        const int n = nbase + q;
        const float qx = src[3 * n], qy = src[3 * n + 1], qz = src[3 * n + 2];
        int cx = min((int)(qx * 10.0f), 9);
        int cy = min((int)(qy * 10.0f), 9);
        int cz = min((int)(qz * 10.0f), 9);
        int z0 = max(cz - 1, 0), z1 = min(cz + 1, 9);
        int ez = z1 - z0 + 1;
        // 9 z-contiguous cell runs (fixed trip-count -> arrays stay in regs).
        int rs[9], rp[9];
        int total = 0;
        #pragma unroll
        for (int u = 0; u < 9; ++u) {
            int ix = cx + (u / 3) - 1;
            int iy = cy + (u % 3) - 1;
            bool ok = (ix >= 0) && (ix <= 9) && (iy >= 0) && (iy <= 9);
            int c0 = ok ? ((ix * 10 + iy) * 10 + z0) : 0;
            int s = __builtin_amdgcn_readfirstlane(cellStart[c0]);
            int e = __builtin_amdgcn_readfirstlane(cellStart[c0 + ez]);
            rs[u] = s; rp[u] = total;
            total += ok ? (e - s) : 0;
        }
        // Candidate chunks of 64.
        for (int base = 0; base < total; base += 64) {
            int j = base + lane;
            bool inb = (j < total);
            int pos = rs[0] + j - rp[0];
            #pragma unroll
            for (int u = 1; u < 9; ++u)
                if (j >= rp[u]) pos = rs[u] + j - rp[u];  // last match wins
            pos = inb ? pos : 0;
            float ax = spx[pos], ay = spy[pos], az = spz[pos];
            int aidx = (int)sidx[pos];
            float dx = ax - qx, dy = ay - qy, dz = az - qz;
            float ds = fmaf(dz, dz, fmaf(dy, dy, dx * dx));
            bool qual = inb && (ds <= RAD2);
            unsigned long long m = __ballot(qual);
            if (m) {
                if (qual) {
                    unsigned r = __builtin_amdgcn_mbcnt_lo((unsigned)m, 0u);
                    r = __builtin_amdgcn_mbcnt_hi((unsigned)(m >> 32), r);
                    int w = qn + (int)r;
                    if (w < QCAP) { qds[wid][w] = ds; qid[wid][w] = aidx; }
                }
                qn += (int)__popcll(m);
            }
        }
        // Rank qualifiers by original index; slot = rank, fill handled later.
        int qc = qn > QCAP ? QCAP : qn;       // qc >= 1 (self qualifies, ds=0)
        bool act = (lane < qc);
        float myds = qds[wid][act ? lane : 0];
        int myid = act ? qid[wid][lane] : 0x7fffffff;
        int rank = 0;
        for (int j2 = 0; j2 < qc; ++j2)
            rank += (qid[wid][j2] < myid) ? 1 : 0;
        if (act && rank < NS) buf[(wid << 2) + q][rank] = myds;
        if (lane == 0) cnts[(wid << 2) + q] = qc < NS ? qc : NS;
        qn = 0;
    }
    __syncthreads();

    // ---- Epilogue: lane i of wave 0 handles block point i.
    if (tid < 64) {
        int cnt = cnts[tid];
        float s[NS];
        float first = buf[tid][0];   // ds of smallest-index qualifier
        #pragma unroll
        for (int j = 0; j < NS; ++j) {
            float v = buf[tid][j];
            s[j] = (j < cnt) ? v : first;
        }
        // Partial selection sort: smallest 5 ascending into s[0..4]
        #pragma unroll
        for (int i = 0; i < 5; ++i) {
            #pragma unroll
            for (int j = i + 1; j < NS; ++j) {
                float lo = fminf(s[i], s[j]);
                float hi = fmaxf(s[i], s[j]);
                s[i] = lo; s[j] = hi;
            }
        }
        float acc = 0.0f;
        #pragma unroll
        for (int i = 1; i < 5; ++i) {
            float c = (s[i] < EPSV) ? EPSV : s[i];
            acc += 0.1f - sqrtf(c) * expf(-c / H2);
        }
        #pragma unroll
        for (int o = 32; o >= 1; o >>= 1)
            acc += __shfl_down(acc, o, 64);
        if (tid == 0) atomicAdd(out, acc * SCALE);
    }
}

extern "C" void kernel_launch(void* const* d_in, const int* in_sizes, int n_in,
                              void* d_out, int out_size, void* d_ws, size_t ws_size,
                              hipStream_t stream) {
    const float* pred = (const float*)d_in[0];
    float* out = (float*)d_out;
    // d_out is re-poisoned to 0xAA before every timed launch — zero it ourselves.
    hipMemsetAsync(out, 0, sizeof(float), stream);
    density_loss_kernel<<<dim3(NB * 64), dim3(1024), 0, stream>>>(pred, out);
}